// Round 8
// baseline (1959.891 us; speedup 1.0000x reference)
//
#include <hip/hip_runtime.h>
#include <stdint.h>
#include <stddef.h>

// ============================================================================
// SL2Net forward, MI355X. Round 8: RESUBMIT of R3-R7 (broker timeouts — the
// SeedSequence-mix bugfix has never been benched). No source changes.
//   numpy's SeedSequence._mix is  (x*MIX_MULT_L - y*MIX_MULT_R) ^ >>16
//   (randutils seed_seq_fe), NOT an XOR combine. R2's XOR made every PCG
//   seed wrong -> every T-matrix wrong at O(1) -> absmax error 1.67.
//
// Pipeline:
//   hipMemsetAsync  : zero variance accumulators in ws
//   k_prep          : block 0 regenerates the 15 T-matrices (numpy-compatible
//                     PCG64+ziggurat); blocks 1..320 compute per-(d,c)
//                     sum/sumsq partials (f64 atomics into ws)
//   k_main          : per 16-batch tile: normalize on the fly, build per-degree
//                     feature chunks in LDS, fp32 register-tiled GEMM vs w_d,
//                     fused MLP for degree 0.
//
// ws layout: [0,8008) T floats | [8192,13312) 320*2 f64 accumulators
// ============================================================================

// ---------------- problem constant tables (all constexpr -> folded) ---------
constexpr int PM_[15]   = {1,1,1,1,1,2,2,2,2,3,3,3,4,4,5};
constexpr int PN_[15]   = {1,2,3,4,5,2,3,4,5,3,4,5,4,5,5};
constexpr int TOFF_[15] = {0,1,5,14,30,55,71,107,171,271,352,496,721,977,1377};
constexpr int SEED_[15] = {1001,1002,1003,1004,1005,2002,2003,2004,2005,
                           3003,3004,3005,4004,4005,5005};
// per-degree: #contributions, flat offset into CPAIR/CROFF, chunk tile, out base
constexpr int CNT_[9]  = {6,5,8,6,7,3,3,1,1};
constexpr int COFF_[9] = {0,6,11,19,25,32,35,38,39};
constexpr int TC_[9]   = {6,5,4,3,2,2,1,1,1};
constexpr int BASE_[9] = {0,1,3,6,10,15,21,28,36};
// contributions per degree, in reference concat order: pair index (-1 = self xn[d])
constexpr int CPAIR_[40] = {
  -1, 0, 5, 9,12,14,          // d0
  -1, 1, 6,10,13,             // d1
  -1, 2, 5, 7, 9,11,12,14,    // d2
  -1, 3, 6, 8,10,13,          // d3
  -1, 4, 7, 9,11,12,14,       // d4
   8,10,13,                   // d5
  11,12,14,                   // d6
  13,                         // d7
  14 };                       // d8
constexpr int CROFF_[40] = {
   0, 0, 3, 8,15,24,
   0, 0, 4,10,18,
   0, 0, 0, 5, 5,12,12,21,
   0, 0, 0, 6, 6,14,
   0, 0, 0, 0, 7, 7,16,
   0, 0, 8,
   0, 0, 9,
   0,
   0 };

struct Args {
  const float* x[5];
  const float* bn[5];
  const float* w1; const float* b1;
  const float* w2; const float* b2;
  const float* w3; const float* b3;
  const float* wd[9];
  float* out;
  float* ws;
};

// ---------------- numpy-compatible RNG ------------------------------------
struct Pcg { __uint128_t st, inc; };

__device__ __forceinline__ uint64_t pcg_next(Pcg& g) {
  const __uint128_t mul =
      (((__uint128_t)0x2360ed051fc65da4ULL) << 64) | 0x4385df649fccf645ULL;
  g.st = g.st * mul + g.inc;
  const uint64_t xo = (uint64_t)(g.st >> 64) ^ (uint64_t)g.st;
  const unsigned rot = (unsigned)(g.st >> 122);
  return (xo >> rot) | (xo << ((64u - rot) & 63u));
}
__device__ __forceinline__ double pcg_dbl(Pcg& g) {
  return (double)(pcg_next(g) >> 11) * (1.0 / 9007199254740992.0);
}
__device__ __forceinline__ uint32_t hmix(uint32_t v, uint32_t& hc) {
  v ^= hc; hc *= 0x931e8875u; v *= hc; v ^= v >> 16; return v;
}
// SeedSequence(seed).generate_state(4, uint64) -> PCG64 init
__device__ void pcg_seed(Pcg& g, uint32_t entropy) {
  uint32_t hc = 0x43b0d7e5u;
  uint32_t pool[4];
  pool[0] = hmix(entropy, hc);
  pool[1] = hmix(0u, hc);
  pool[2] = hmix(0u, hc);
  pool[3] = hmix(0u, hc);
  for (int s = 0; s < 4; ++s)
    for (int d = 0; d < 4; ++d)
      if (s != d) {
        uint32_t h = hmix(pool[s], hc);
        // numpy SeedSequence._mix (randutils seed_seq_fe):
        //   result = x*MIX_MULT_L - y*MIX_MULT_R; result ^= result>>16
        uint32_t r = pool[d] * 0xca01f9ddu - h * 0x4973f715u;
        r ^= r >> 16;
        pool[d] = r;
      }
  uint32_t hb = 0x8b51f9ddu;
  uint32_t w[8];
  for (int i = 0; i < 8; ++i) {
    uint32_t dv = pool[i & 3];
    dv ^= hb; hb *= 0x58f38dedu; dv *= hb; dv ^= dv >> 16;
    w[i] = dv;
  }
  const uint64_t su0 = ((uint64_t)w[1] << 32) | w[0];
  const uint64_t su1 = ((uint64_t)w[3] << 32) | w[2];
  const uint64_t su2 = ((uint64_t)w[5] << 32) | w[4];
  const uint64_t su3 = ((uint64_t)w[7] << 32) | w[6];
  const __uint128_t initstate = (((__uint128_t)su0) << 64) | su1;
  const __uint128_t initseq   = (((__uint128_t)su2) << 64) | su3;
  const __uint128_t mul =
      (((__uint128_t)0x2360ed051fc65da4ULL) << 64) | 0x4385df649fccf645ULL;
  g.inc = (initseq << 1) | 1;
  g.st  = 0;
  g.st  = g.st * mul + g.inc;   // step
  g.st += initstate;
  g.st  = g.st * mul + g.inc;   // step
}

__device__ double std_normal(Pcg& g, const unsigned long long* ki,
                             const double* wi, const double* fi) {
  const double nor_r     = 3.6541528853610087963519472518;
  const double nor_inv_r = 0.27366123732975827203338247596;
  for (;;) {
    uint64_t r = pcg_next(g);
    const int idx = (int)(r & 0xff);
    r >>= 8;
    const int sgn = (int)(r & 1);
    const uint64_t rabs = (r >> 1) & 0x000fffffffffffffULL;
    double x = (double)rabs * wi[idx];
    if (sgn) x = -x;
    if (rabs < ki[idx]) return x;
    if (idx == 0) {
      double xx, yy;
      do {
        xx = -nor_inv_r * log1p(-pcg_dbl(g));
        yy = -log1p(-pcg_dbl(g));
      } while (yy + yy <= xx * xx);
      return ((rabs >> 8) & 1) ? -(nor_r + xx) : (nor_r + xx);
    } else {
      if ((fi[idx - 1] - fi[idx]) * pcg_dbl(g) + fi[idx] < exp(-0.5 * x * x))
        return x;
    }
  }
}

// ---------------- k_prep: T-gen (block 0) + variance (blocks 1..320) --------
__global__ __launch_bounds__(256) void k_prep(Args A) {
  __shared__ double s_wi[256];
  __shared__ double s_fi[256];
  __shared__ unsigned long long s_ki[256];
  __shared__ double red[512];
  const int tid = threadIdx.x;

  if (blockIdx.x == 0) {
    if (tid == 0) {
      // Marsaglia-Tsang ziggurat tables, 256 layers, m = 2^52.
      // Invariant: exp(-0.5*dn_new^2) == vn/dn_old + exp(-0.5*dn_old^2),
      // so the chain needs only {div, log, sqrt} per layer (no exp).
      // Cross-check: wi[0] = q/2^52 ~ 8.68e-16 == numpy wi_double[0].
      const double m1 = 4503599627370496.0;   // 2^52
      double dn = 3.6541528853610087963519472518;
      double tn = dn;
      const double f_r = exp(-0.5 * dn * dn);
      const double vn  = dn * f_r +
          1.2533141373155002512 * erfc(dn * 0.7071067811865475244);
      const double q = vn / f_r;
      s_ki[0] = (unsigned long long)((dn / q) * m1);
      s_ki[1] = 0ull;
      s_wi[0]   = q / m1;
      s_wi[255] = dn / m1;
      s_fi[0]   = 1.0;
      s_fi[255] = f_r;
      double f = f_r;
      for (int i = 254; i >= 1; --i) {
        const double t = vn / dn + f;          // == exp(-0.5*dn_new^2)
        dn = sqrt(-2.0 * log(t));
        f = t;
        s_ki[i + 1] = (unsigned long long)((dn / tn) * m1);
        tn = dn;
        s_fi[i] = t;
        s_wi[i] = dn / m1;
      }
    }
    __syncthreads();
    if (tid < 15) {
      Pcg g;
      pcg_seed(g, (uint32_t)SEED_[tid]);
      const int m = PM_[tid], n = PN_[tid], mn = m * n;
      const double sq = sqrt((double)mn);
      float* dst = A.ws + TOFF_[tid];
      const int tot = mn * mn;
      for (int t = 0; t < tot; ++t) {
        const double z = std_normal(g, s_ki, s_wi, s_fi);
        dst[t] = (float)(z / sq);
      }
    }
    return;
  }

  // variance partials: 64 blocks per degree, each covers 256 b-rows
  const int vb  = blockIdx.x - 1;
  const int d   = vb >> 6;
  const int sub = vb & 63;
  const int dp1 = d + 1;
  const int c   = tid & 63;
  const int bg  = tid >> 6;
  const float* xp = A.x[d];
  double s1 = 0.0, s2 = 0.0;
  const int bbase = sub * 256;
  for (int ib = 0; ib < 64; ++ib) {
    const int b = bbase + bg + 4 * ib;
    const float* row = xp + ((size_t)b * 64 + c) * dp1;
    for (int p = 0; p < dp1; ++p) {
      const float v = row[p];
      s1 += v;
      s2 += (double)v * (double)v;
    }
  }
  red[tid]       = s1;
  red[256 + tid] = s2;
  __syncthreads();
  if (tid < 64) {
    const double a1 = red[tid] + red[tid + 64] + red[tid + 128] + red[tid + 192];
    const double a2 = red[256 + tid] + red[256 + tid + 64] +
                      red[256 + tid + 128] + red[256 + tid + 192];
    double* acc = (double*)((char*)A.ws + 8192);
    atomicAdd(&acc[(d * 64 + tid) * 2],     a1);
    atomicAdd(&acc[(d * 64 + tid) * 2 + 1], a2);
  }
}

// ---------------- degree-0 MLP (feats0 resident in sF as [384][17]) ---------
__device__ void mlp_body(const Args& A, float* __restrict__ sF, int tid, int b0) {
  float* h1 = sF + 6528;   // [128][17]
  float* h2 = sF + 8704;   // [128][17]
  // M1: h1 = lrelu(f0 @ w1^T + b1)
  {
    const int hg = tid >> 4, b = tid & 15;
    float a[4];
#pragma unroll
    for (int i = 0; i < 4; ++i) a[i] = A.b1[4 * hg + i];
    for (int k = 0; k < 384; k += 4) {
      float fv[4];
#pragma unroll
      for (int z = 0; z < 4; ++z) fv[z] = sF[(k + z) * 17 + b];
#pragma unroll
      for (int i = 0; i < 4; ++i) {
        const float4 wv = *(const float4*)(A.w1 + (size_t)(4 * hg + i) * 384 + k);
        a[i] += wv.x * fv[0] + wv.y * fv[1] + wv.z * fv[2] + wv.w * fv[3];
      }
    }
#pragma unroll
    for (int i = 0; i < 4; ++i) {
      const float v = a[i];
      h1[(4 * hg + i) * 17 + b] = (v > 0.f) ? v : 0.01f * v;
    }
  }
  __syncthreads();
  // M2: h2 = lrelu(h1 @ w2^T + b2)
  {
    const int hg = tid >> 4, b = tid & 15;
    float a[4];
#pragma unroll
    for (int i = 0; i < 4; ++i) a[i] = A.b2[4 * hg + i];
    for (int k = 0; k < 128; k += 4) {
      float hv[4];
#pragma unroll
      for (int z = 0; z < 4; ++z) hv[z] = h1[(k + z) * 17 + b];
#pragma unroll
      for (int i = 0; i < 4; ++i) {
        const float4 wv = *(const float4*)(A.w2 + (size_t)(4 * hg + i) * 128 + k);
        a[i] += wv.x * hv[0] + wv.y * hv[1] + wv.z * hv[2] + wv.w * hv[3];
      }
    }
#pragma unroll
    for (int i = 0; i < 4; ++i) {
      const float v = a[i];
      h2[(4 * hg + i) * 17 + b] = (v > 0.f) ? v : 0.01f * v;
    }
  }
  __syncthreads();
  // M3: f3 = h2 @ w3^T + b3  -> overwrite f0 region (dead)
  {
    const int kg = tid >> 3, bg = tid & 7;   // k = kg*6+kk, b = 2*bg(+1)
    float a[6][2];
#pragma unroll
    for (int kk = 0; kk < 6; ++kk) { a[kk][0] = 0.f; a[kk][1] = 0.f; }
    for (int k2 = 0; k2 < 128; k2 += 4) {
      float fa[4], fb[4];
#pragma unroll
      for (int z = 0; z < 4; ++z) {
        fa[z] = h2[(k2 + z) * 17 + 2 * bg];
        fb[z] = h2[(k2 + z) * 17 + 2 * bg + 1];
      }
#pragma unroll
      for (int kk = 0; kk < 6; ++kk) {
        const float4 wv = *(const float4*)(A.w3 + (size_t)(kg * 6 + kk) * 128 + k2);
        a[kk][0] += wv.x * fa[0] + wv.y * fa[1] + wv.z * fa[2] + wv.w * fa[3];
        a[kk][1] += wv.x * fb[0] + wv.y * fb[1] + wv.z * fb[2] + wv.w * fb[3];
      }
    }
#pragma unroll
    for (int kk = 0; kk < 6; ++kk) {
      const int k = kg * 6 + kk;
      const float bv = A.b3[k];
      sF[k * 17 + 2 * bg]     = a[kk][0] + bv;
      sF[k * 17 + 2 * bg + 1] = a[kk][1] + bv;
    }
  }
  __syncthreads();
  // M4: out[:, :, 0] = w0 @ f3
  {
    const int og = tid >> 4, b = tid & 15;
    float a[2] = {0.f, 0.f};
    for (int k = 0; k < 384; k += 4) {
      float fv[4];
#pragma unroll
      for (int z = 0; z < 4; ++z) fv[z] = sF[(k + z) * 17 + b];
#pragma unroll
      for (int i = 0; i < 2; ++i) {
        const float4 wv = *(const float4*)(A.wd[0] + (size_t)(2 * og + i) * 384 + k);
        a[i] += wv.x * fv[0] + wv.y * fv[1] + wv.z * fv[2] + wv.w * fv[3];
      }
    }
#pragma unroll
    for (int i = 0; i < 2; ++i)
      A.out[((size_t)(b0 + b) * 64 + (2 * og + i)) * 45] = a[i];
  }
}

// ---------------- per-degree body (fully compile-time shapes) ---------------
template <int D>
__device__ void degree_body(const Args& A, const float* __restrict__ sT,
                            const float* __restrict__ sScale,
                            float* __restrict__ sF, int tid, int b0) {
  constexpr int dp1 = D + 1;
  constexpr int Nn  = 16 * dp1;       // bs dimension
  constexpr int Np  = Nn + 1;         // padded (odd) LDS row
  constexpr int cnt = CNT_[D];
  constexpr int tc  = TC_[D];
  constexpr int TN  = (dp1 + 1) / 2;  // ceil(Nn/32)
  const int go = tid >> 5, gb = tid & 31;
  float acc[4][TN];
#pragma unroll
  for (int i = 0; i < 4; ++i)
#pragma unroll
    for (int j = 0; j < TN; ++j) acc[i][j] = 0.f;

#pragma unroll
  for (int t0 = 0; t0 < cnt; t0 += tc) {
    const int tcc = (tc < cnt - t0) ? tc : (cnt - t0);
    // -------- build feature chunk: sF[k][bs], k=(tl*64+c), bs=b*dp1+r -------
#pragma unroll
    for (int half = 0; half < 2; ++half) {
      const int it = tid + half * 512;
      const int b = it >> 6, c = it & 63;
#pragma unroll
      for (int tl = 0; tl < tc; ++tl) {
        if (tl >= tcc) break;
        const int ci = COFF_[D] + t0 + tl;
        const int pr = CPAIR_[ci];
        float* dst = &sF[(tl * 64 + c) * Np + b * dp1];
        if (pr < 0) {
          // self term: xn[D]
          const float sc = sScale[D * 64 + c];
          const float* xp = A.x[D] + ((size_t)(b0 + b) * 64 + c) * dp1;
#pragma unroll
          for (int r = 0; r < dp1; ++r) dst[r] = xp[r] * sc;
        } else {
          const int m = PM_[pr], n = PN_[pr];   // compile-time after unroll
          const float sci = sScale[(m - 1) * 64 + c];
          const float scj = sScale[(n - 1) * 64 + c];
          const float* xpi = A.x[m - 1] + ((size_t)(b0 + b) * 64 + c) * m;
          const float* xpj = A.x[n - 1] + ((size_t)(b0 + b) * 64 + c) * n;
          float xi[5], xj[5];
#pragma unroll
          for (int a = 0; a < 5; ++a) if (a < m) xi[a] = xpi[a] * sci;
#pragma unroll
          for (int e = 0; e < 5; ++e) if (e < n) xj[e] = xpj[e] * scj;
          const float* Tb = sT + TOFF_[pr] + CROFF_[ci] * (m * n);
#pragma unroll
          for (int r = 0; r < dp1; ++r) {
            float v = 0.f;
#pragma unroll
            for (int a = 0; a < 5; ++a) {
              if (a >= m) break;
              float pa = 0.f;
#pragma unroll
              for (int e = 0; e < 5; ++e) {
                if (e >= n) break;
                pa += Tb[r * (m * n) + a * n + e] * xj[e];
              }
              v += xi[a] * pa;
            }
            dst[r] = v;
          }
        }
      }
    }
    __syncthreads();
    if (D >= 1) {
      // -------- GEMM-accumulate: acc[o][bs] += w_d[o,kg] * sF[k][bs] --------
      const int Kc = tcc * 64;
      const float* wd = A.wd[D];
      constexpr int Kd = CNT_[D] * 64;
      for (int k4 = 0; k4 < Kc; k4 += 4) {
        float f[4][TN];
#pragma unroll
        for (int z = 0; z < 4; ++z)
#pragma unroll
          for (int j = 0; j < TN; ++j) {
            const int bs = gb + 32 * j;
            f[z][j] = (bs < Nn) ? sF[(k4 + z) * Np + bs] : 0.f;
          }
        const int kg = t0 * 64 + k4;
#pragma unroll
        for (int i = 0; i < 4; ++i) {
          const float4 wv = *(const float4*)(wd + (size_t)(4 * go + i) * Kd + kg);
#pragma unroll
          for (int j = 0; j < TN; ++j)
            acc[i][j] += wv.x * f[0][j] + wv.y * f[1][j] +
                         wv.z * f[2][j] + wv.w * f[3][j];
        }
      }
    } else {
      mlp_body(A, sF, tid, b0);   // D==0: single chunk, fused MLP + out slot 0
    }
    __syncthreads();
  }
  if (D >= 1) {
    // -------- write out[b, o, BASE+s] --------
#pragma unroll
    for (int j = 0; j < TN; ++j) {
      const int bs = gb + 32 * j;
      if (bs < Nn) {
        const int b = bs / dp1, s = bs - b * dp1;
        float* op = A.out + ((size_t)(b0 + b) * 64 + 4 * go) * 45 + BASE_[D] + s;
        op[0]   = acc[0][j];
        op[45]  = acc[1][j];
        op[90]  = acc[2][j];
        op[135] = acc[3][j];
      }
    }
  }
}

// ---------------- main fused kernel ----------------------------------------
__global__ __launch_bounds__(512) void k_main(Args A) {
  __shared__ float sT[2002];
  __shared__ float sScale[320];
  __shared__ float sF[12544];
  const int tid = threadIdx.x;
  const int b0 = blockIdx.x * 16;
  for (int i = tid; i < 2002; i += 512) sT[i] = A.ws[i];
  if (tid < 320) {
    const int d = tid >> 6, c = tid & 63;
    const double* accd = (const double*)((const char*)A.ws + 8192);
    const double nn   = 16384.0 * (d + 1);
    const double mean = accd[2 * tid] / nn;
    const double var  = accd[2 * tid + 1] / nn - mean * mean;
    sScale[tid] = A.bn[d][c] / sqrtf((float)var + 1e-5f);
  }
  __syncthreads();
  degree_body<0>(A, sT, sScale, sF, tid, b0);
  degree_body<1>(A, sT, sScale, sF, tid, b0);
  degree_body<2>(A, sT, sScale, sF, tid, b0);
  degree_body<3>(A, sT, sScale, sF, tid, b0);
  degree_body<4>(A, sT, sScale, sF, tid, b0);
  degree_body<5>(A, sT, sScale, sF, tid, b0);
  degree_body<6>(A, sT, sScale, sF, tid, b0);
  degree_body<7>(A, sT, sScale, sF, tid, b0);
  degree_body<8>(A, sT, sScale, sF, tid, b0);
}

// ---------------- launch ----------------------------------------------------
extern "C" void kernel_launch(void* const* d_in, const int* in_sizes, int n_in,
                              void* d_out, int out_size, void* d_ws, size_t ws_size,
                              hipStream_t stream) {
  (void)in_sizes; (void)n_in; (void)out_size; (void)ws_size;
  Args A;
  for (int d = 0; d < 5; ++d) {
    A.x[d]  = (const float*)d_in[2 * d];
    A.bn[d] = (const float*)d_in[2 * d + 1];
  }
  A.w1 = (const float*)d_in[10]; A.b1 = (const float*)d_in[11];
  A.w2 = (const float*)d_in[12]; A.b2 = (const float*)d_in[13];
  A.w3 = (const float*)d_in[14]; A.b3 = (const float*)d_in[15];
  for (int k = 0; k < 9; ++k) A.wd[k] = (const float*)d_in[16 + k];
  A.out = (float*)d_out;
  A.ws  = (float*)d_ws;

  hipMemsetAsync((char*)d_ws + 8192, 0, 320 * 2 * sizeof(double), stream);
  hipLaunchKernelGGL(k_prep, dim3(321), dim3(256), 0, stream, A);
  hipLaunchKernelGGL(k_main, dim3(1024), dim3(512), 0, stream, A);
}